// Round 6
// baseline (541.722 us; speedup 1.0000x reference)
//
#include <hip/hip_runtime.h>
#include <stdint.h>
#include <math.h>

#define NTOK  8192
#define DIM   1024
#define HID   2048
#define NE    8

typedef __attribute__((ext_vector_type(8))) short short8;
typedef __attribute__((ext_vector_type(4))) float f32x4;

__device__ __forceinline__ unsigned short f2bf(float f) {
  union { float f; unsigned u; } a; a.f = f;
  unsigned u = a.u;
  u += 0x7fffu + ((u >> 16) & 1u);   // RNE
  return (unsigned short)(u >> 16);
}

__device__ __forceinline__ float bf2f(unsigned short s) {
  union { unsigned u; float f; } a; a.u = ((unsigned)s) << 16;
  return a.f;
}

// async global->LDS, 16B per lane. lds dest = wave-uniform base + lane*16.
__device__ __forceinline__ void gl2lds16(const unsigned short* g, unsigned short* l) {
  __builtin_amdgcn_global_load_lds(
      (const __attribute__((address_space(1))) unsigned int*)g,
      (__attribute__((address_space(3))) unsigned int*)l,
      16, 0, 0);
}

// fp32 [R][C] 64x64 tile -> bf16 [C][R], via padded LDS tile. 256 threads.
__device__ __forceinline__ void transpose_tile(
    const float* __restrict__ ine, unsigned short* __restrict__ oute,
    int R, int C, unsigned short (*tileT)[72], int t) {
  #pragma unroll
  for (int i = 0; i < 4; i++) {
    int idx = t + i * 256;
    int r = idx >> 4, c = (idx & 15) * 4;
    float4 v = *(const float4*)(ine + (size_t)r * C + c);
    tileT[c + 0][r] = f2bf(v.x);
    tileT[c + 1][r] = f2bf(v.y);
    tileT[c + 2][r] = f2bf(v.z);
    tileT[c + 3][r] = f2bf(v.w);
  }
  __syncthreads();
  #pragma unroll
  for (int i = 0; i < 2; i++) {
    int idx = t + i * 256;
    int rr = idx >> 3, cc = (idx & 7) * 8;
    *(uint4*)(oute + (size_t)rr * R + cc) = *(const uint4*)(&tileT[rr][cc]);
  }
}

// one wave per token: gate = x @ Wg, top-2 + softmax -> packed idx + probs.
// Fuses x -> bf16 cast. Block 0 zeroes cnt (race-free: route runs next dispatch).
__global__ __launch_bounds__(256) void gate_kernel(
    const float* __restrict__ x, const float* __restrict__ Wg,
    unsigned short* __restrict__ xb,
    int* __restrict__ eidx, float* __restrict__ eprob, int* __restrict__ cnt) {
  if (blockIdx.x == 0 && threadIdx.x < NE) cnt[threadIdx.x] = 0;
  int wid = threadIdx.x >> 6;
  int lane = threadIdx.x & 63;
  int t = blockIdx.x * 4 + wid;
  const float* xr = x + (size_t)t * DIM;
  unsigned short* xbr = xb + (size_t)t * DIM;
  float acc[NE];
  #pragma unroll
  for (int e = 0; e < NE; e++) acc[e] = 0.f;
  #pragma unroll
  for (int it = 0; it < DIM / 64; it++) {
    int d = it * 64 + lane;
    float xv = xr[d];
    xbr[d] = f2bf(xv);
    const float4* wr = (const float4*)(Wg + d * NE);
    float4 w0 = wr[0], w1 = wr[1];
    acc[0] += xv * w0.x; acc[1] += xv * w0.y; acc[2] += xv * w0.z; acc[3] += xv * w0.w;
    acc[4] += xv * w1.x; acc[5] += xv * w1.y; acc[6] += xv * w1.z; acc[7] += xv * w1.w;
  }
  #pragma unroll
  for (int e = 0; e < NE; e++) {
    float v = acc[e];
    #pragma unroll
    for (int off = 32; off > 0; off >>= 1) v += __shfl_xor(v, off);
    acc[e] = v;
  }
  if (lane == 0) {
    int i0 = 0; float v0 = acc[0];
    #pragma unroll
    for (int e = 1; e < NE; e++) if (acc[e] > v0) { v0 = acc[e]; i0 = e; }
    int i1 = -1; float v1 = -3.4e38f;
    #pragma unroll
    for (int e = 0; e < NE; e++) if (e != i0 && acc[e] > v1) { v1 = acc[e]; i1 = e; }
    float e1 = expf(v1 - v0);
    float p0 = 1.f / (1.f + e1);
    float p1 = e1 / (1.f + e1);
    eidx[t] = i0 | (i1 << 16);
    eprob[2 * t] = p0;
    eprob[2 * t + 1] = p1;
  }
}

// Fused: blocks 0..31 route (256 tokens each); blocks 32.. transpose W1,W2.
__global__ __launch_bounds__(256) void prep_kernel(
    const float* __restrict__ W1, const float* __restrict__ W2,
    unsigned short* __restrict__ w1t, unsigned short* __restrict__ w2t,
    const int* __restrict__ eidx,
    int* __restrict__ cnt, int* __restrict__ tok_list, int* __restrict__ slotpos) {
  __shared__ unsigned short tileT[64][72];
  __shared__ int lhist[NE];
  __shared__ int gbase[NE];
  int b = blockIdx.x;
  int tid = threadIdx.x;
  if (b < 32) {
    // route: per-block LDS histogram, 8 global atomics per block, scatter
    if (tid < NE) lhist[tid] = 0;
    __syncthreads();
    int t = b * 256 + tid;
    int pk = eidx[t];
    int i0 = pk & 0xffff, i1 = pk >> 16;
    int l0 = atomicAdd(&lhist[i0], 1);
    int l1 = atomicAdd(&lhist[i1], 1);
    __syncthreads();
    if (tid < NE) gbase[tid] = atomicAdd(&cnt[tid], lhist[tid]);
    __syncthreads();
    int s0 = gbase[i0] + l0;
    int s1 = gbase[i1] + l1;
    tok_list[i0 * NTOK + s0] = t;
    tok_list[i1 * NTOK + s1] = t;
    slotpos[2 * t] = (i0 << 16) | s0;
    slotpos[2 * t + 1] = (i1 << 16) | s1;
    return;
  }
  int rem = b - 32;
  int which = rem >> 12;            // 0 -> W1, 1 -> W2
  rem &= 4095;
  int bx = rem & 31, by = (rem >> 5) & 15, e = rem >> 9;
  const float* in = which ? W2 : W1;
  unsigned short* out = which ? w2t : w1t;
  const float* ine = in + (size_t)e * DIM * HID + (size_t)(by * 64) * HID + bx * 64;
  unsigned short* oute = out + (size_t)e * DIM * HID + (size_t)(bx * 64) * DIM + by * 64;
  transpose_tile(ine, oute, DIM, HID, tileT, tid);
}

// Fused: blocks 0..16383 grouped dual GEMM1; blocks 16384.. transpose W3.
// GEMM1: a=A@W1t^T, v=A@W2t^T; h=swish(a)*v -> hbuf. M=128 N=64(x2) K-step 64.
__global__ __launch_bounds__(256, 4) void gemm1_kernel(
    const unsigned short* __restrict__ xb,
    const unsigned short* __restrict__ w1t,
    const unsigned short* __restrict__ w2t,
    const float* __restrict__ W3, unsigned short* __restrict__ w3t,
    const int* __restrict__ cnt,
    const int* __restrict__ tok_list,
    unsigned short* __restrict__ hbuf) {
  __shared__ __align__(16) unsigned char smem[33280];
  unsigned short* As  = (unsigned short*)smem;            // 16384 B
  unsigned short* Bs1 = (unsigned short*)(smem + 16384);  // 8192 B
  unsigned short* Bs2 = (unsigned short*)(smem + 24576);  // 8192 B
  int* toks = (int*)(smem + 32768);                       // 512 B

  int b = blockIdx.x;
  int tid = threadIdx.x;

  if (b >= 16384) {
    // W3 transpose: fp32 [e][HID][DIM] -> bf16 [e][DIM][HID]
    unsigned short (*tileT)[72] = (unsigned short (*)[72])smem;
    int rem = b - 16384;
    int bx = rem & 15, by = (rem >> 4) & 31, e = rem >> 9;
    const float* ine = W3 + (size_t)e * HID * DIM + (size_t)(by * 64) * DIM + bx * 64;
    unsigned short* oute = w3t + (size_t)e * HID * DIM + (size_t)(bx * 64) * HID + by * 64;
    transpose_tile(ine, oute, HID, DIM, tileT, tid);
    return;
  }

  int nt = b & 31, mt = (b >> 5) & 63, e = b >> 11;
  int count = cnt[e];
  if (mt * 128 >= count) return;

  if (tid < 128) {
    int r = mt * 128 + tid;
    toks[tid] = tok_list[e * NTOK + (r < count ? r : 0)];
  }
  __syncthreads();

  int wid = tid >> 6, lane = tid & 63;
  int wm = wid >> 1, wn = wid & 1;
  int m16 = lane & 15, quad = lane >> 4;

  const unsigned short* W1e = w1t + (size_t)e * HID * DIM + (size_t)(nt * 64) * DIM;
  const unsigned short* W2e = w2t + (size_t)e * HID * DIM + (size_t)(nt * 64) * DIM;

  const unsigned short* aptr[4];
  #pragma unroll
  for (int i = 0; i < 4; i++) {
    int slot = wid * 256 + i * 64 + lane;
    int r = slot >> 3, c = slot & 7, g = c ^ (r & 7);
    aptr[i] = xb + (size_t)toks[r] * DIM + g * 8;
  }
  const unsigned short *b1p[2], *b2p[2];
  #pragma unroll
  for (int i = 0; i < 2; i++) {
    int slot = wid * 128 + i * 64 + lane;
    int r = slot >> 3, c = slot & 7, g = c ^ (r & 7);
    b1p[i] = W1e + (size_t)r * DIM + g * 8;
    b2p[i] = W2e + (size_t)r * DIM + g * 8;
  }

  f32x4 acc1[4][2], acc2[4][2];
  f32x4 zz = {0.f, 0.f, 0.f, 0.f};
  #pragma unroll
  for (int i = 0; i < 4; i++)
    #pragma unroll
    for (int j = 0; j < 2; j++) { acc1[i][j] = zz; acc2[i][j] = zz; }

  for (int k0 = 0; k0 < DIM; k0 += 64) {
    #pragma unroll
    for (int i = 0; i < 4; i++)
      gl2lds16(aptr[i] + k0, As + (wid * 256 + i * 64) * 8);
    #pragma unroll
    for (int i = 0; i < 2; i++) {
      gl2lds16(b1p[i] + k0, Bs1 + (wid * 128 + i * 64) * 8);
      gl2lds16(b2p[i] + k0, Bs2 + (wid * 128 + i * 64) * 8);
    }
    __syncthreads();
    #pragma unroll
    for (int ks = 0; ks < 2; ks++) {
      int ga = ks * 4 + quad;
      short8 af[4], b1f[2], b2f[2];
      #pragma unroll
      for (int fm = 0; fm < 4; fm++) {
        int ra = wm * 64 + fm * 16 + m16;
        af[fm] = *(const short8*)(As + ra * 64 + (ga ^ (ra & 7)) * 8);
      }
      #pragma unroll
      for (int fn = 0; fn < 2; fn++) {
        int rb = wn * 32 + fn * 16 + m16;
        b1f[fn] = *(const short8*)(Bs1 + rb * 64 + (ga ^ (rb & 7)) * 8);
        b2f[fn] = *(const short8*)(Bs2 + rb * 64 + (ga ^ (rb & 7)) * 8);
      }
      #pragma unroll
      for (int fm = 0; fm < 4; fm++)
        #pragma unroll
        for (int fn = 0; fn < 2; fn++) {
          acc1[fm][fn] = __builtin_amdgcn_mfma_f32_16x16x32_bf16(af[fm], b1f[fn], acc1[fm][fn], 0, 0, 0);
          acc2[fm][fn] = __builtin_amdgcn_mfma_f32_16x16x32_bf16(af[fm], b2f[fn], acc2[fm][fn], 0, 0, 0);
        }
    }
    __syncthreads();
  }

  int hb = 0;
  #pragma unroll
  for (int j = 0; j < NE; j++) if (j < e) hb += cnt[j];
  #pragma unroll
  for (int fm = 0; fm < 4; fm++)
    #pragma unroll
    for (int fn = 0; fn < 2; fn++)
      #pragma unroll
      for (int r = 0; r < 4; r++) {
        int row = wm * 64 + fm * 16 + quad * 4 + r;   // C/D: col=lane&15, row=quad*4+reg
        if (mt * 128 + row < count) {
          float a = acc1[fm][fn][r];
          float v = acc2[fm][fn][r];
          float h = (a / (1.f + __expf(-a))) * v;
          int col = nt * 64 + wn * 32 + fn * 16 + m16;
          hbuf[(size_t)(hb + mt * 128 + row) * HID + col] = f2bf(h);
        }
      }
}

// y = hbuf @ W3t^T -> grouped ybuf (bf16, plain stores). M=64 N=128 K-step 64.
__global__ __launch_bounds__(256, 4) void gemm2_kernel(
    const unsigned short* __restrict__ hbuf,
    const unsigned short* __restrict__ w3t,
    const int* __restrict__ cnt,
    unsigned short* __restrict__ ybuf) {
  int e = blockIdx.z;
  int count = cnt[e];
  int mt = blockIdx.y;
  if (mt * 64 >= count) return;
  int nt = blockIdx.x;
  int hb = 0;
  #pragma unroll
  for (int j = 0; j < NE; j++) if (j < e) hb += cnt[j];

  __shared__ __align__(16) unsigned short As[64 * 64];
  __shared__ __align__(16) unsigned short Bs[128 * 64];

  int tid = threadIdx.x;
  int wid = tid >> 6, lane = tid & 63;   // wid = wn in 0..3
  int m16 = lane & 15, quad = lane >> 4;

  const unsigned short* W3e = w3t + (size_t)e * DIM * HID + (size_t)(nt * 128) * HID;

  const unsigned short *aptr[2], *bptr[4];
  #pragma unroll
  for (int i = 0; i < 2; i++) {
    int slot = tid + 256 * i;
    int r = slot >> 3, c = slot & 7, g = c ^ (r & 7);
    int gr = mt * 64 + r;
    int rc = (gr < count) ? gr : (count - 1);
    aptr[i] = hbuf + (size_t)(hb + rc) * HID + g * 8;
  }
  #pragma unroll
  for (int i = 0; i < 4; i++) {
    int slot = tid + 256 * i;
    int r = slot >> 3, c = slot & 7, g = c ^ (r & 7);
    bptr[i] = W3e + (size_t)r * HID + g * 8;
  }

  f32x4 acc[4][2];
  f32x4 zz = {0.f, 0.f, 0.f, 0.f};
  #pragma unroll
  for (int i = 0; i < 4; i++)
    #pragma unroll
    for (int j = 0; j < 2; j++) acc[i][j] = zz;

  for (int k0 = 0; k0 < HID; k0 += 64) {
    #pragma unroll
    for (int i = 0; i < 2; i++)
      gl2lds16(aptr[i] + k0, As + (i * 256 + (tid & ~63)) * 8);
    #pragma unroll
    for (int i = 0; i < 4; i++)
      gl2lds16(bptr[i] + k0, Bs + (i * 256 + (tid & ~63)) * 8);
    __syncthreads();
    #pragma unroll
    for (int ks = 0; ks < 2; ks++) {
      int ga = ks * 4 + quad;
      short8 af[4], bf[2];
      #pragma unroll
      for (int fm = 0; fm < 4; fm++) {
        int ra = fm * 16 + m16;
        af[fm] = *(const short8*)(As + ra * 64 + (ga ^ (ra & 7)) * 8);
      }
      #pragma unroll
      for (int fn = 0; fn < 2; fn++) {
        int rb = wid * 32 + fn * 16 + m16;
        bf[fn] = *(const short8*)(Bs + rb * 64 + (ga ^ (rb & 7)) * 8);
      }
      #pragma unroll
      for (int fm = 0; fm < 4; fm++)
        #pragma unroll
        for (int fn = 0; fn < 2; fn++)
          acc[fm][fn] = __builtin_amdgcn_mfma_f32_16x16x32_bf16(af[fm], bf[fn], acc[fm][fn], 0, 0, 0);
    }
    __syncthreads();
  }

  #pragma unroll
  for (int fm = 0; fm < 4; fm++)
    #pragma unroll
    for (int fn = 0; fn < 2; fn++)
      #pragma unroll
      for (int r = 0; r < 4; r++) {
        int row = fm * 16 + quad * 4 + r;
        if (mt * 64 + row < count) {
          int col = nt * 128 + wid * 32 + fn * 16 + m16;
          ybuf[(size_t)(hb + mt * 64 + row) * DIM + col] = f2bf(acc[fm][fn][r]);
        }
      }
}

// out[t] = p0 * ybuf[row0] + p1 * ybuf[row1]; 8 tokens per block, bf16 gather.
__global__ __launch_bounds__(256) void combine_kernel(
    const unsigned short* __restrict__ ybuf, const int* __restrict__ cnt,
    const int* __restrict__ slotpos, const float* __restrict__ eprob,
    float* __restrict__ out) {
  __shared__ int sbase[NE];
  if (threadIdx.x == 0) {
    int s = 0;
    #pragma unroll
    for (int e = 0; e < NE; e++) { sbase[e] = s; s += cnt[e]; }
  }
  __syncthreads();
  int d = threadIdx.x * 4;
  #pragma unroll
  for (int i = 0; i < 8; i++) {
    int t = blockIdx.x * 8 + i;
    int ps0 = slotpos[2 * t], ps1 = slotpos[2 * t + 1];
    int r0 = sbase[ps0 >> 16] + (ps0 & 0xffff);
    int r1 = sbase[ps1 >> 16] + (ps1 & 0xffff);
    float p0 = eprob[2 * t], p1 = eprob[2 * t + 1];
    ushort4 y0 = *(const ushort4*)(ybuf + (size_t)r0 * DIM + d);
    ushort4 y1 = *(const ushort4*)(ybuf + (size_t)r1 * DIM + d);
    float4 o;
    o.x = p0 * bf2f(y0.x) + p1 * bf2f(y1.x);
    o.y = p0 * bf2f(y0.y) + p1 * bf2f(y1.y);
    o.z = p0 * bf2f(y0.z) + p1 * bf2f(y1.z);
    o.w = p0 * bf2f(y0.w) + p1 * bf2f(y1.w);
    *(float4*)(out + (size_t)t * DIM + d) = o;
  }
}

extern "C" void kernel_launch(void* const* d_in, const int* in_sizes, int n_in,
                              void* d_out, int out_size, void* d_ws, size_t ws_size,
                              hipStream_t stream) {
  const float* x  = (const float*)d_in[0];
  const float* Wg = (const float*)d_in[1];
  const float* W1 = (const float*)d_in[2];
  const float* W2 = (const float*)d_in[3];
  const float* W3 = (const float*)d_in[4];
  float* out = (float*)d_out;

  // workspace layout (~185 MB total); ybuf (bf16, 33.5 MB) aliases w1t (dead by gemm2)
  char* ws = (char*)d_ws;
  size_t off = 0;
  int* cnt = (int*)(ws + off); off += 256;
  int* eidx = (int*)(ws + off); off += (size_t)NTOK * 4;
  float* eprob = (float*)(ws + off); off += (size_t)NTOK * 2 * 4;
  int* slotpos = (int*)(ws + off); off += (size_t)NTOK * 2 * 4;
  int* tok_list = (int*)(ws + off); off += (size_t)NE * NTOK * 4;
  unsigned short* xb  = (unsigned short*)(ws + off); off += (size_t)NTOK * DIM * 2;
  unsigned short* w1t = (unsigned short*)(ws + off); off += (size_t)NE * DIM * HID * 2;
  unsigned short* w2t = (unsigned short*)(ws + off); off += (size_t)NE * DIM * HID * 2;
  unsigned short* w3t = (unsigned short*)(ws + off); off += (size_t)NE * DIM * HID * 2;
  unsigned short* hbuf = (unsigned short*)(ws + off); off += (size_t)NTOK * 2 * HID * 2;
  unsigned short* ybuf = w1t;   // 33.5 MB fits in |w1t| (67 MB)

  gate_kernel<<<NTOK / 4, 256, 0, stream>>>(x, Wg, xb, eidx, eprob, cnt);
  prep_kernel<<<32 + 2 * 4096, 256, 0, stream>>>(W1, W2, w1t, w2t, eidx, cnt, tok_list, slotpos);
  gemm1_kernel<<<16384 + 4096, 256, 0, stream>>>(xb, w1t, w2t, W3, w3t, cnt, tok_list, hbuf);
  gemm2_kernel<<<dim3(DIM / 128, NTOK / 64, NE), 256, 0, stream>>>(hbuf, w3t, cnt, ybuf);
  combine_kernel<<<NTOK / 8, 256, 0, stream>>>(ybuf, cnt, slotpos, eprob, out);
}